// Round 8
// baseline (295.725 us; speedup 1.0000x reference)
//
#include <hip/hip_runtime.h>

// MHSA. Inputs fp32, output fp32. B=4, T=2048, D=1024, H=16, hd=64.
// R15: re-anchor after 3 failed rounds (R12 crash, R13/R14 absmax races --
// all variants of the 36KB/4-blk attn dbuf; mechanism never identified).
//  (a) attn reverted to R9 VERBATIM (passed twice, 83.2 us; measured faster
//      than the R11 dbuf's 88.2 anyway).
//  (b) vtrans kernel DELETED: gemm<0> writes V directly transposed to
//      [b,h,d,t] (index swap in the which==2 branch). Saves 16 MB of
//      traffic + one launch; V stores become 4x-consecutive-u16 scatter.

typedef __attribute__((ext_vector_type(8))) short bf16x8;
typedef __attribute__((ext_vector_type(8))) unsigned short u16x8;
typedef __attribute__((ext_vector_type(4))) float f32x4;
typedef __attribute__((ext_vector_type(16))) float f32x16;

#define DEV static __device__ __forceinline__

DEV unsigned short f2b(float f) {  // RTNE f32 -> bf16
  union { float f; unsigned int i; } v; v.f = f;
  unsigned int x = v.i;
  return (unsigned short)((x + 0x7FFFu + ((x >> 16) & 1u)) >> 16);
}

DEV f32x4 mfma16(bf16x8 a, bf16x8 b, f32x4 c) {
  return __builtin_amdgcn_mfma_f32_16x16x32_bf16(a, b, c, 0, 0, 0);
}
DEV f32x16 mfma32(bf16x8 a, bf16x8 b, f32x16 c) {
  return __builtin_amdgcn_mfma_f32_32x32x16_bf16(a, b, c, 0, 0, 0);
}

DEV void gl_lds16(const unsigned short* g, unsigned short* l) {
  __builtin_amdgcn_global_load_lds(
      (const __attribute__((address_space(1))) unsigned int*)g,
      (__attribute__((address_space(3))) unsigned int*)l, 16, 0, 0);
}

// cvt two f32 pairs to packed bf16, then swap upper-half(a) <-> lower-half(b)
// across the wave. Yields two A-frag words (see layout notes in attn).
DEV void pk_swap(float a0, float a1, float b0, float b1,
                 unsigned int& w_lo, unsigned int& w_hi) {
  unsigned int a, b;
  asm("v_cvt_pk_bf16_f32 %0, %1, %2" : "=v"(a) : "v"(a0), "v"(a1));
  asm("v_cvt_pk_bf16_f32 %0, %1, %2" : "=v"(b) : "v"(b0), "v"(b1));
  asm("v_permlane32_swap_b32 %0, %1" : "+v"(a), "+v"(b));
  w_lo = a; w_hi = b;
}

// ---------------------------------------------------------------- convert
__global__ __launch_bounds__(256) void f32_to_bf16(
    const float* __restrict__ in, unsigned short* __restrict__ out, int n4) {
  const int i = (blockIdx.x * 256 + threadIdx.x) * 4;
  if (i >= n4 * 4) return;
  const float4 v = *(const float4*)(in + i);
  ushort4 o;
  o.x = f2b(v.x); o.y = f2b(v.y); o.z = f2b(v.z); o.w = f2b(v.w);
  *(ushort4*)(out + i) = o;
}

// ---------------------------------------------------------------- transpose
__global__ __launch_bounds__(256) void transpose_f32_bf16(
    const float* __restrict__ in, unsigned short* __restrict__ out,
    int R, int C) {
  __shared__ float tile[32][33];
  const int tx = threadIdx.x & 31, ty = threadIdx.x >> 5;
  const int c0 = blockIdx.x * 32, r0 = blockIdx.y * 32;
#pragma unroll
  for (int i = 0; i < 32; i += 8)
    tile[ty + i][tx] = in[(size_t)(r0 + ty + i) * C + (c0 + tx)];
  __syncthreads();
#pragma unroll
  for (int i = 0; i < 32; i += 8)
    out[(size_t)(c0 + ty + i) * R + (r0 + tx)] = f2b(tile[tx][ty + i]);
}

// ---------------------------------------------------------------- GEMM
// C[M,N] = A[M,K]*Bt[N,K]^T + bias. 128x128 tile, BK=32, 4 waves, m97-style
// global_load_lds staging.
// MODE 0: scatter bf16 to Q [b,h,t,d], K [b,h,t,d], V^T [b,h,d,t]
//         (Q prescaled 0.125*log2e; V^T written directly, no vtrans pass).
// MODE 1: fp32 row-major output (final projection).
#define QSCALE 0.18033688f  // 0.125 * log2(e)
template <int MODE>
__global__ __launch_bounds__(256, 2) void gemm_bt(
    const unsigned short* __restrict__ A, const unsigned short* __restrict__ Bt,
    const float* __restrict__ bias, void* __restrict__ out_v,
    int M, int N, int K) {
  __shared__ __align__(16) unsigned short As[128 * 32];
  __shared__ __align__(16) unsigned short Bs[128 * 32];
  const int tid = threadIdx.x;
  const int w = tid >> 6, l = tid & 63, g = l >> 4, ln = l & 15;
  const int m0 = blockIdx.y * 128, n0 = blockIdx.x * 128;
  const int wm = (w & 1) * 64, wn = (w >> 1) * 64;

  f32x4 acc[4][4];
#pragma unroll
  for (int i = 0; i < 4; ++i)
#pragma unroll
    for (int j = 0; j < 4; ++j) acc[i][j] = (f32x4){0.f, 0.f, 0.f, 0.f};

  const unsigned short* Ab = A + (size_t)m0 * K;
  const unsigned short* Bb = Bt + (size_t)n0 * K;
  const int c0 = tid, c1 = tid + 256;
  const int ar0 = c0 >> 2, ak0 = (c0 & 3) * 8;
  const int ar1 = c1 >> 2, ak1 = (c1 & 3) * 8;

  for (int k0 = 0; k0 < K; k0 += 32) {
    gl_lds16(Ab + (size_t)ar0 * K + k0 + ak0, &As[c0 * 8]);
    gl_lds16(Ab + (size_t)ar1 * K + k0 + ak1, &As[c1 * 8]);
    gl_lds16(Bb + (size_t)ar0 * K + k0 + ak0, &Bs[c0 * 8]);
    gl_lds16(Bb + (size_t)ar1 * K + k0 + ak1, &Bs[c1 * 8]);
    __syncthreads();
    bf16x8 af[4], bf[4];
#pragma unroll
    for (int mi = 0; mi < 4; ++mi)
      af[mi] = *(const bf16x8*)&As[(wm + mi * 16 + ln) * 32 + g * 8];
#pragma unroll
    for (int ni = 0; ni < 4; ++ni)
      bf[ni] = *(const bf16x8*)&Bs[(wn + ni * 16 + ln) * 32 + g * 8];
#pragma unroll
    for (int mi = 0; mi < 4; ++mi)
#pragma unroll
      for (int ni = 0; ni < 4; ++ni)
        acc[mi][ni] = mfma16(af[mi], bf[ni], acc[mi][ni]);
    __syncthreads();
  }

#pragma unroll
  for (int mi = 0; mi < 4; ++mi) {
#pragma unroll
    for (int ni = 0; ni < 4; ++ni) {
      const int row0 = m0 + wm + mi * 16 + 4 * g;
      const int col = n0 + wn + ni * 16 + ln;
      const float bv = bias[col];
#pragma unroll
      for (int r = 0; r < 4; ++r) {
        float v = acc[mi][ni][r] + bv;
        const int row = row0 + r;
        if (MODE == 0) {
          const int which = col >> 10;           // 0=Q 1=K 2=V
          const int h = (col >> 6) & 15;
          const int dd = col & 63;
          const int b = row >> 11, t = row & 2047;
          if (which == 2) {
            // V^T [b,h,d,t] -- direct transposed write (slot 3 = Vtw)
            unsigned short* dst = (unsigned short*)out_v + (size_t)3 * 8388608u;
            dst[(((size_t)(b * 16 + h)) * 64 + dd) * 2048 + t] = f2b(v);
          } else {
            unsigned short* dst = (unsigned short*)out_v + (size_t)which * 8388608u;
            if (which == 0) v *= QSCALE;
            dst[(((size_t)(b * 16 + h)) * 2048 + t) * 64 + dd] = f2b(v);
          }
        } else {
          ((float*)out_v)[(size_t)row * N + col] = v;
        }
      }
    }
  }
}

// ---------------------------------------------------------------- attention
// One block per (bh, 128-q tile); 4 waves, wave w owns q rows [32w, 32w+32).
// mfma 32x32x16. Q prescaled (log2 domain), no online max, deferred
// l-normalization.  [R9 body, verbatim -- passed rounds 2 & 3 at 83.2 us]
// SWAPPED QK^T: S^T = mfma32(K_frag, Q_frag) -> C/D col=l&31 is q, rows are
// keys at crow(r,lh)=(r&3)+8*(r>>2)+4*lh. Each lane owns P[q=l32][32 keys/nb].
// PV A-frag (m=q=l&31, k=lh*8+j) built in-register via pk_swap.
// Row-sums: os = mfma32(ap[ks], ones, os) -> os[r] = lsum(q=crow(r,lh)),
// identical layout to o[db][r]; epilogue needs no shuffles.
__global__ __launch_bounds__(256, 2) void attn(
    const unsigned short* __restrict__ Q, const unsigned short* __restrict__ K,
    const unsigned short* __restrict__ Vtg, unsigned short* __restrict__ Y) {
  __shared__ __align__(16) unsigned short Qs[128 * 72];
  __shared__ __align__(16) unsigned short Ks[64 * 72];     // [key][d]
  __shared__ __align__(16) unsigned short Vt[64 * 72];     // [d][key]

  const int tid = threadIdx.x;
  const int w = tid >> 6, l = tid & 63;
  const int l32 = l & 31, lh = l >> 5;       // half-wave select
  const int bh = blockIdx.y;
  const int q0 = blockIdx.x * 128;

  const unsigned short* Qb = Q + (size_t)bh * 131072;    // [t][d]
  const unsigned short* Kb = K + (size_t)bh * 131072;    // [t][d]
  const unsigned short* Vb = Vtg + (size_t)bh * 131072;  // [d][t]

  // stage Q: 128x64 bf16 -> stride-72 rows
#pragma unroll
  for (int i = 0; i < 4; ++i) {
    const int c = tid + i * 256;   // 1024 chunks
    u16x8 v = *(const u16x8*)(Qb + (size_t)q0 * 64 + c * 8);
    *(u16x8*)&Qs[(c >> 3) * 72 + (c & 7) * 8] = v;
  }
  __syncthreads();
  // hoist Q fragments (B-operand now; same (idx=l&31, k) mapping as A)
  bf16x8 aq[4];
#pragma unroll
  for (int kb = 0; kb < 4; ++kb)
    aq[kb] = *(const bf16x8*)&Qs[(w * 32 + l32) * 72 + kb * 16 + lh * 8];

  // ones B-frag (bf16 1.0 = 0x3F80) for the row-sum MFMA
  const short one_b = (short)0x3F80;
  const bf16x8 vones = (bf16x8){one_b, one_b, one_b, one_b,
                                one_b, one_b, one_b, one_b};

  f32x16 o[2], os;
#pragma unroll
  for (int db = 0; db < 2; ++db)
#pragma unroll
    for (int r = 0; r < 16; ++r) o[db][r] = 0.f;
#pragma unroll
  for (int r = 0; r < 16; ++r) os[r] = 0.f;

  for (int kt = 0; kt < 32; ++kt) {
    // stage K tile [key][d] and V tile [d][key] (V^T global)
#pragma unroll
    for (int i = 0; i < 2; ++i) {
      const int c = tid + i * 256;
      const int row = c >> 3, cc = (c & 7) * 8;
      u16x8 kv = *(const u16x8*)(Kb + (size_t)kt * 4096 + c * 8);
      u16x8 vv = *(const u16x8*)(Vb + (size_t)row * 2048 + kt * 64 + cc);
      *(u16x8*)&Ks[row * 72 + cc] = kv;
      *(u16x8*)&Vt[row * 72 + cc] = vv;
    }
    __syncthreads();

    // S^T = K Q^T : per wave 64k x 32q, two 32-key blocks (A=K, B=Q)
    f32x16 s[2];
#pragma unroll
    for (int nb = 0; nb < 2; ++nb) {
#pragma unroll
      for (int r = 0; r < 16; ++r) s[nb][r] = 0.f;
#pragma unroll
      for (int kb = 0; kb < 4; ++kb) {
        bf16x8 bk = *(const bf16x8*)&Ks[(nb * 32 + l32) * 72 + kb * 16 + lh * 8];
        s[nb] = mfma32(bk, aq[kb], s[nb]);
      }
    }

    // raw v_exp_f32 + in-register P->bf16 A-fragments (no LDS round-trip)
    bf16x8 ap[4];
#pragma unroll
    for (int nb = 0; nb < 2; ++nb) {
      float pe[16];
#pragma unroll
      for (int r = 0; r < 16; ++r)
        pe[r] = __builtin_amdgcn_exp2f(s[nb][r]);
      union { unsigned int wd[4]; bf16x8 v; } u0, u1;
      pk_swap(pe[0], pe[1], pe[4], pe[5], u0.wd[0], u0.wd[2]);
      pk_swap(pe[2], pe[3], pe[6], pe[7], u0.wd[1], u0.wd[3]);
      pk_swap(pe[8], pe[9], pe[12], pe[13], u1.wd[0], u1.wd[2]);
      pk_swap(pe[10], pe[11], pe[14], pe[15], u1.wd[1], u1.wd[3]);
      ap[2 * nb + 0] = u0.v;   // keys nb*32 + [0,16)
      ap[2 * nb + 1] = u1.v;   // keys nb*32 + [16,32)
    }

    // PV: A = P (in-register), B = V^T; row-sum on the MFMA pipe
#pragma unroll
    for (int ks = 0; ks < 4; ++ks) {
      os = mfma32(ap[ks], vones, os);
#pragma unroll
      for (int db = 0; db < 2; ++db) {
        bf16x8 bv = *(const bf16x8*)&Vt[(db * 32 + l32) * 72 + ks * 16 + lh * 8];
        o[db] = mfma32(ap[ks], bv, o[db]);
      }
    }
    __syncthreads();  // all waves done with Ks/Vt before next staging
  }

  // os[r] = sum over all keys of P[q=crow(r,lh)] -- same layout as o[db][r]
  float iv[16];
#pragma unroll
  for (int r = 0; r < 16; ++r) iv[r] = 1.f / os[r];

  // epilogue: y[b, t, h*64 + d]
  const int b = bh >> 4, h = bh & 15;
#pragma unroll
  for (int db = 0; db < 2; ++db)
#pragma unroll
    for (int r = 0; r < 16; ++r) {
      const int row = (r & 3) + 8 * (r >> 2) + 4 * lh;
      const int t = q0 + w * 32 + row;
      Y[(size_t)(b * 2048 + t) * 1024 + h * 64 + db * 32 + l32] =
          f2b(o[db][r] * iv[r]);
    }
}

// ---------------------------------------------------------------- launch
extern "C" void kernel_launch(void* const* d_in, const int* in_sizes, int n_in,
                              void* d_out, int out_size, void* d_ws, size_t ws_size,
                              hipStream_t stream) {
  const float* x     = (const float*)d_in[0];
  const float* Wqkv  = (const float*)d_in[1];
  const float* bqkv  = (const float*)d_in[2];
  const float* Wproj = (const float*)d_in[3];
  const float* bproj = (const float*)d_in[4];
  float* out = (float*)d_out;
  unsigned short* ws = (unsigned short*)d_ws;

  unsigned short* xbf    = ws;
  unsigned short* Yw     = xbf;  // alias: x dead after gemm_bt<0>
  unsigned short* WqkvT  = xbf + 8388608;
  unsigned short* WprojT = WqkvT + 3072 * 1024;
  unsigned short* Qw     = WprojT + 1024 * 1024;
  unsigned short* Kw     = Qw + 8388608;   // [b,h,t,d]
  unsigned short* Vw     = Kw + 8388608;   // (unused -- V written as V^T)
  unsigned short* Vtw    = Vw + 8388608;   // [b,h,d,t], written by gemm<0>
  (void)Vw;

  f32_to_bf16<<<8192, 256, 0, stream>>>(x, xbf, 2097152);
  transpose_f32_bf16<<<dim3(96, 32), 256, 0, stream>>>(Wqkv, WqkvT, 1024, 3072);
  transpose_f32_bf16<<<dim3(32, 32), 256, 0, stream>>>(Wproj, WprojT, 1024, 1024);
  gemm_bt<0><<<dim3(24, 64), 256, 0, stream>>>(xbf, WqkvT, bqkv, Qw, 8192, 3072, 1024);
  attn<<<dim3(16, 64), 256, 0, stream>>>(Qw, Kw, Vtw, Yw);
  gemm_bt<1><<<dim3(8, 64), 256, 0, stream>>>(Yw, WprojT, bproj, out, 8192, 1024, 1024);
}

// Round 9
// 283.556 us; speedup vs baseline: 1.0429x; 1.0429x over previous
//
#include <hip/hip_runtime.h>

// MHSA. Inputs fp32, output fp32. B=4, T=2048, D=1024, H=16, hd=64.
// R16: gemm_bt fixes (both mechanism-verified from R15 counters):
//  (a) V^T epilogue store vectorized: quad's 4 consecutive t -> one ushort4
//      (was 4x 2B scattered stores; caused gemm0 85.8->99.4 in R15).
//  (b) T2 XOR swizzle on As/Bs (rule 21, both-sides): stage with
//      inverse-swizzled GLOBAL column (LDS dest linear for gl_lds16), read
//      with xg = g ^ ((ln>>1)&3). Kills the 8-way row-stride-64B conflict
//      (SQ_LDS_BANK_CONFLICT 6.29M every round, ~10% of gemm cycles).
// attn stays R9-verbatim (passed 3x); vtrans stays deleted.

typedef __attribute__((ext_vector_type(8))) short bf16x8;
typedef __attribute__((ext_vector_type(8))) unsigned short u16x8;
typedef __attribute__((ext_vector_type(4))) float f32x4;
typedef __attribute__((ext_vector_type(16))) float f32x16;

#define DEV static __device__ __forceinline__

DEV unsigned short f2b(float f) {  // RTNE f32 -> bf16
  union { float f; unsigned int i; } v; v.f = f;
  unsigned int x = v.i;
  return (unsigned short)((x + 0x7FFFu + ((x >> 16) & 1u)) >> 16);
}

DEV f32x4 mfma16(bf16x8 a, bf16x8 b, f32x4 c) {
  return __builtin_amdgcn_mfma_f32_16x16x32_bf16(a, b, c, 0, 0, 0);
}
DEV f32x16 mfma32(bf16x8 a, bf16x8 b, f32x16 c) {
  return __builtin_amdgcn_mfma_f32_32x32x16_bf16(a, b, c, 0, 0, 0);
}

DEV void gl_lds16(const unsigned short* g, unsigned short* l) {
  __builtin_amdgcn_global_load_lds(
      (const __attribute__((address_space(1))) unsigned int*)g,
      (__attribute__((address_space(3))) unsigned int*)l, 16, 0, 0);
}

// cvt two f32 pairs to packed bf16, then swap upper-half(a) <-> lower-half(b)
// across the wave. Yields two A-frag words (see layout notes in attn).
DEV void pk_swap(float a0, float a1, float b0, float b1,
                 unsigned int& w_lo, unsigned int& w_hi) {
  unsigned int a, b;
  asm("v_cvt_pk_bf16_f32 %0, %1, %2" : "=v"(a) : "v"(a0), "v"(a1));
  asm("v_cvt_pk_bf16_f32 %0, %1, %2" : "=v"(b) : "v"(b0), "v"(b1));
  asm("v_permlane32_swap_b32 %0, %1" : "+v"(a), "+v"(b));
  w_lo = a; w_hi = b;
}

// ---------------------------------------------------------------- convert
__global__ __launch_bounds__(256) void f32_to_bf16(
    const float* __restrict__ in, unsigned short* __restrict__ out, int n4) {
  const int i = (blockIdx.x * 256 + threadIdx.x) * 4;
  if (i >= n4 * 4) return;
  const float4 v = *(const float4*)(in + i);
  ushort4 o;
  o.x = f2b(v.x); o.y = f2b(v.y); o.z = f2b(v.z); o.w = f2b(v.w);
  *(ushort4*)(out + i) = o;
}

// ---------------------------------------------------------------- transpose
__global__ __launch_bounds__(256) void transpose_f32_bf16(
    const float* __restrict__ in, unsigned short* __restrict__ out,
    int R, int C) {
  __shared__ float tile[32][33];
  const int tx = threadIdx.x & 31, ty = threadIdx.x >> 5;
  const int c0 = blockIdx.x * 32, r0 = blockIdx.y * 32;
#pragma unroll
  for (int i = 0; i < 32; i += 8)
    tile[ty + i][tx] = in[(size_t)(r0 + ty + i) * C + (c0 + tx)];
  __syncthreads();
#pragma unroll
  for (int i = 0; i < 32; i += 8)
    out[(size_t)(c0 + ty + i) * R + (r0 + tx)] = f2b(tile[tx][ty + i]);
}

// ---------------------------------------------------------------- GEMM
// C[M,N] = A[M,K]*Bt[N,K]^T + bias. 128x128 tile, BK=32, 4 waves, m97-style
// global_load_lds staging.
// LDS swizzle (T2, rule 21): row r's physical 16B-chunk p holds logical
// chunk p ^ ((r>>1)&3); staged by inverse-swizzling the global source col
// (LDS dest stays linear, as gl_lds16 requires); frag reads use
// xg = g ^ ((ln>>1)&3)  (row&7 == ln&7 for all quads here).
// MODE 0: scatter bf16 to Q [b,h,t,d], K [b,h,t,d], V^T [b,h,d,t]
//         (Q prescaled 0.125*log2e; V^T quad stored as one ushort4).
// MODE 1: fp32 row-major output (final projection).
#define QSCALE 0.18033688f  // 0.125 * log2(e)
template <int MODE>
__global__ __launch_bounds__(256, 2) void gemm_bt(
    const unsigned short* __restrict__ A, const unsigned short* __restrict__ Bt,
    const float* __restrict__ bias, void* __restrict__ out_v,
    int M, int N, int K) {
  __shared__ __align__(16) unsigned short As[128 * 32];
  __shared__ __align__(16) unsigned short Bs[128 * 32];
  const int tid = threadIdx.x;
  const int w = tid >> 6, l = tid & 63, g = l >> 4, ln = l & 15;
  const int m0 = blockIdx.y * 128, n0 = blockIdx.x * 128;
  const int wm = (w & 1) * 64, wn = (w >> 1) * 64;

  f32x4 acc[4][4];
#pragma unroll
  for (int i = 0; i < 4; ++i)
#pragma unroll
    for (int j = 0; j < 4; ++j) acc[i][j] = (f32x4){0.f, 0.f, 0.f, 0.f};

  const unsigned short* Ab = A + (size_t)m0 * K;
  const unsigned short* Bb = Bt + (size_t)n0 * K;
  const int c0 = tid, c1 = tid + 256;
  const int ar0 = c0 >> 2, ar1 = c1 >> 2;
  // inverse-swizzled source chunk (involution: same XOR both sides)
  const int ak0 = (((c0 & 3) ^ ((ar0 >> 1) & 3))) * 8;
  const int ak1 = (((c1 & 3) ^ ((ar1 >> 1) & 3))) * 8;
  // swizzled read chunk for this lane's fragment rows (row&7 == ln&7)
  const int xg = (g ^ ((ln >> 1) & 3)) * 8;

  for (int k0 = 0; k0 < K; k0 += 32) {
    gl_lds16(Ab + (size_t)ar0 * K + k0 + ak0, &As[c0 * 8]);
    gl_lds16(Ab + (size_t)ar1 * K + k0 + ak1, &As[c1 * 8]);
    gl_lds16(Bb + (size_t)ar0 * K + k0 + ak0, &Bs[c0 * 8]);
    gl_lds16(Bb + (size_t)ar1 * K + k0 + ak1, &Bs[c1 * 8]);
    __syncthreads();
    bf16x8 af[4], bf[4];
#pragma unroll
    for (int mi = 0; mi < 4; ++mi)
      af[mi] = *(const bf16x8*)&As[(wm + mi * 16 + ln) * 32 + xg];
#pragma unroll
    for (int ni = 0; ni < 4; ++ni)
      bf[ni] = *(const bf16x8*)&Bs[(wn + ni * 16 + ln) * 32 + xg];
#pragma unroll
    for (int mi = 0; mi < 4; ++mi)
#pragma unroll
      for (int ni = 0; ni < 4; ++ni)
        acc[mi][ni] = mfma16(af[mi], bf[ni], acc[mi][ni]);
    __syncthreads();
  }

#pragma unroll
  for (int mi = 0; mi < 4; ++mi) {
#pragma unroll
    for (int ni = 0; ni < 4; ++ni) {
      const int row0 = m0 + wm + mi * 16 + 4 * g;
      const int col = n0 + wn + ni * 16 + ln;
      const float bv = bias[col];
      if (MODE == 0) {
        const int which = col >> 10;           // 0=Q 1=K 2=V
        const int h = (col >> 6) & 15;
        const int dd = col & 63;
        const int b = row0 >> 11, t0 = row0 & 2047;  // quad stays in one b
        if (which == 2) {
          // V^T [b,h,d,t]: 4 consecutive t -> one 8B store
          unsigned short* dst = (unsigned short*)out_v + (size_t)3 * 8388608u;
          ushort4 o;
          o.x = f2b(acc[mi][ni][0] + bv);
          o.y = f2b(acc[mi][ni][1] + bv);
          o.z = f2b(acc[mi][ni][2] + bv);
          o.w = f2b(acc[mi][ni][3] + bv);
          *(ushort4*)&dst[(((size_t)(b * 16 + h)) * 64 + dd) * 2048 + t0] = o;
        } else {
          unsigned short* dst = (unsigned short*)out_v + (size_t)which * 8388608u;
#pragma unroll
          for (int r = 0; r < 4; ++r) {
            float v = acc[mi][ni][r] + bv;
            if (which == 0) v *= QSCALE;
            dst[(((size_t)(b * 16 + h)) * 2048 + t0 + r) * 64 + dd] = f2b(v);
          }
        }
      } else {
#pragma unroll
        for (int r = 0; r < 4; ++r)
          ((float*)out_v)[(size_t)(row0 + r) * N + col] = acc[mi][ni][r] + bv;
      }
    }
  }
}

// ---------------------------------------------------------------- attention
// One block per (bh, 128-q tile); 4 waves, wave w owns q rows [32w, 32w+32).
// mfma 32x32x16. Q prescaled (log2 domain), no online max, deferred
// l-normalization.  [R9 body, verbatim -- passed 3x at ~83 us]
// SWAPPED QK^T: S^T = mfma32(K_frag, Q_frag) -> C/D col=l&31 is q, rows are
// keys at crow(r,lh)=(r&3)+8*(r>>2)+4*lh. Each lane owns P[q=l32][32 keys/nb].
// PV A-frag (m=q=l&31, k=lh*8+j) built in-register via pk_swap.
// Row-sums: os = mfma32(ap[ks], ones, os) -> os[r] = lsum(q=crow(r,lh)),
// identical layout to o[db][r]; epilogue needs no shuffles.
__global__ __launch_bounds__(256, 2) void attn(
    const unsigned short* __restrict__ Q, const unsigned short* __restrict__ K,
    const unsigned short* __restrict__ Vtg, unsigned short* __restrict__ Y) {
  __shared__ __align__(16) unsigned short Qs[128 * 72];
  __shared__ __align__(16) unsigned short Ks[64 * 72];     // [key][d]
  __shared__ __align__(16) unsigned short Vt[64 * 72];     // [d][key]

  const int tid = threadIdx.x;
  const int w = tid >> 6, l = tid & 63;
  const int l32 = l & 31, lh = l >> 5;       // half-wave select
  const int bh = blockIdx.y;
  const int q0 = blockIdx.x * 128;

  const unsigned short* Qb = Q + (size_t)bh * 131072;    // [t][d]
  const unsigned short* Kb = K + (size_t)bh * 131072;    // [t][d]
  const unsigned short* Vb = Vtg + (size_t)bh * 131072;  // [d][t]

  // stage Q: 128x64 bf16 -> stride-72 rows
#pragma unroll
  for (int i = 0; i < 4; ++i) {
    const int c = tid + i * 256;   // 1024 chunks
    u16x8 v = *(const u16x8*)(Qb + (size_t)q0 * 64 + c * 8);
    *(u16x8*)&Qs[(c >> 3) * 72 + (c & 7) * 8] = v;
  }
  __syncthreads();
  // hoist Q fragments (B-operand now; same (idx=l&31, k) mapping as A)
  bf16x8 aq[4];
#pragma unroll
  for (int kb = 0; kb < 4; ++kb)
    aq[kb] = *(const bf16x8*)&Qs[(w * 32 + l32) * 72 + kb * 16 + lh * 8];

  // ones B-frag (bf16 1.0 = 0x3F80) for the row-sum MFMA
  const short one_b = (short)0x3F80;
  const bf16x8 vones = (bf16x8){one_b, one_b, one_b, one_b,
                                one_b, one_b, one_b, one_b};

  f32x16 o[2], os;
#pragma unroll
  for (int db = 0; db < 2; ++db)
#pragma unroll
    for (int r = 0; r < 16; ++r) o[db][r] = 0.f;
#pragma unroll
  for (int r = 0; r < 16; ++r) os[r] = 0.f;

  for (int kt = 0; kt < 32; ++kt) {
    // stage K tile [key][d] and V tile [d][key] (V^T global)
#pragma unroll
    for (int i = 0; i < 2; ++i) {
      const int c = tid + i * 256;
      const int row = c >> 3, cc = (c & 7) * 8;
      u16x8 kv = *(const u16x8*)(Kb + (size_t)kt * 4096 + c * 8);
      u16x8 vv = *(const u16x8*)(Vb + (size_t)row * 2048 + kt * 64 + cc);
      *(u16x8*)&Ks[row * 72 + cc] = kv;
      *(u16x8*)&Vt[row * 72 + cc] = vv;
    }
    __syncthreads();

    // S^T = K Q^T : per wave 64k x 32q, two 32-key blocks (A=K, B=Q)
    f32x16 s[2];
#pragma unroll
    for (int nb = 0; nb < 2; ++nb) {
#pragma unroll
      for (int r = 0; r < 16; ++r) s[nb][r] = 0.f;
#pragma unroll
      for (int kb = 0; kb < 4; ++kb) {
        bf16x8 bk = *(const bf16x8*)&Ks[(nb * 32 + l32) * 72 + kb * 16 + lh * 8];
        s[nb] = mfma32(bk, aq[kb], s[nb]);
      }
    }

    // raw v_exp_f32 + in-register P->bf16 A-fragments (no LDS round-trip)
    bf16x8 ap[4];
#pragma unroll
    for (int nb = 0; nb < 2; ++nb) {
      float pe[16];
#pragma unroll
      for (int r = 0; r < 16; ++r)
        pe[r] = __builtin_amdgcn_exp2f(s[nb][r]);
      union { unsigned int wd[4]; bf16x8 v; } u0, u1;
      pk_swap(pe[0], pe[1], pe[4], pe[5], u0.wd[0], u0.wd[2]);
      pk_swap(pe[2], pe[3], pe[6], pe[7], u0.wd[1], u0.wd[3]);
      pk_swap(pe[8], pe[9], pe[12], pe[13], u1.wd[0], u1.wd[2]);
      pk_swap(pe[10], pe[11], pe[14], pe[15], u1.wd[1], u1.wd[3]);
      ap[2 * nb + 0] = u0.v;   // keys nb*32 + [0,16)
      ap[2 * nb + 1] = u1.v;   // keys nb*32 + [16,32)
    }

    // PV: A = P (in-register), B = V^T; row-sum on the MFMA pipe
#pragma unroll
    for (int ks = 0; ks < 4; ++ks) {
      os = mfma32(ap[ks], vones, os);
#pragma unroll
      for (int db = 0; db < 2; ++db) {
        bf16x8 bv = *(const bf16x8*)&Vt[(db * 32 + l32) * 72 + ks * 16 + lh * 8];
        o[db] = mfma32(ap[ks], bv, o[db]);
      }
    }
    __syncthreads();  // all waves done with Ks/Vt before next staging
  }

  // os[r] = sum over all keys of P[q=crow(r,lh)] -- same layout as o[db][r]
  float iv[16];
#pragma unroll
  for (int r = 0; r < 16; ++r) iv[r] = 1.f / os[r];

  // epilogue: y[b, t, h*64 + d]
  const int b = bh >> 4, h = bh & 15;
#pragma unroll
  for (int db = 0; db < 2; ++db)
#pragma unroll
    for (int r = 0; r < 16; ++r) {
      const int row = (r & 3) + 8 * (r >> 2) + 4 * lh;
      const int t = q0 + w * 32 + row;
      Y[(size_t)(b * 2048 + t) * 1024 + h * 64 + db * 32 + l32] =
          f2b(o[db][r] * iv[r]);
    }
}

// ---------------------------------------------------------------- launch
extern "C" void kernel_launch(void* const* d_in, const int* in_sizes, int n_in,
                              void* d_out, int out_size, void* d_ws, size_t ws_size,
                              hipStream_t stream) {
  const float* x     = (const float*)d_in[0];
  const float* Wqkv  = (const float*)d_in[1];
  const float* bqkv  = (const float*)d_in[2];
  const float* Wproj = (const float*)d_in[3];
  const float* bproj = (const float*)d_in[4];
  float* out = (float*)d_out;
  unsigned short* ws = (unsigned short*)d_ws;

  unsigned short* xbf    = ws;
  unsigned short* Yw     = xbf;  // alias: x dead after gemm_bt<0>
  unsigned short* WqkvT  = xbf + 8388608;
  unsigned short* WprojT = WqkvT + 3072 * 1024;
  unsigned short* Qw     = WprojT + 1024 * 1024;
  unsigned short* Kw     = Qw + 8388608;   // [b,h,t,d]
  unsigned short* Vw     = Kw + 8388608;   // (unused -- V written as V^T)
  unsigned short* Vtw    = Vw + 8388608;   // [b,h,d,t], written by gemm<0>
  (void)Vw;

  f32_to_bf16<<<8192, 256, 0, stream>>>(x, xbf, 2097152);
  transpose_f32_bf16<<<dim3(96, 32), 256, 0, stream>>>(Wqkv, WqkvT, 1024, 3072);
  transpose_f32_bf16<<<dim3(32, 32), 256, 0, stream>>>(Wproj, WprojT, 1024, 1024);
  gemm_bt<0><<<dim3(24, 64), 256, 0, stream>>>(xbf, WqkvT, bqkv, Qw, 8192, 3072, 1024);
  attn<<<dim3(16, 64), 256, 0, stream>>>(Qw, Kw, Vtw, Yw);
  gemm_bt<1><<<dim3(8, 64), 256, 0, stream>>>(Yw, WprojT, bproj, out, 8192, 1024, 1024);
}

// Round 11
// 267.879 us; speedup vs baseline: 1.1040x; 1.0585x over previous
//
#include <hip/hip_runtime.h>

// MHSA. Inputs fp32, output fp32. B=4, T=2048, D=1024, H=16, hd=64.
// R18: attn BODY IS FROZEN at R9-verbatim (3/3 passed; every restructure
// R12/R13/R14/R17 failed 4/4 -- mechanism never found, stop touching it).
// This round, two zero-sync-structure changes:
//  (a) prep: fuse f32_to_bf16 + both weight transposes (6 -> 4 dispatches;
//      ~12 us/gap of inter-dispatch overhead observed).
//  (b) attn XCD-chunked bijective block swizzle (T1; index remap ONLY):
//      each XCD gets 8 whole bh -> per-XCD L2 serves that bh's K/V for all
//      16 q-tile blocks. attn FETCH was 139.3 MB vs ~50 ideal; staging is
//      on the single-buffer critical path so L2-hits cut real latency.
// gemm_bt keeps R16's swizzle + V^T ushort4 store (verified win).

typedef __attribute__((ext_vector_type(8))) short bf16x8;
typedef __attribute__((ext_vector_type(8))) unsigned short u16x8;
typedef __attribute__((ext_vector_type(4))) float f32x4;
typedef __attribute__((ext_vector_type(16))) float f32x16;

#define DEV static __device__ __forceinline__

DEV unsigned short f2b(float f) {  // RTNE f32 -> bf16
  union { float f; unsigned int i; } v; v.f = f;
  unsigned int x = v.i;
  return (unsigned short)((x + 0x7FFFu + ((x >> 16) & 1u)) >> 16);
}

DEV f32x4 mfma16(bf16x8 a, bf16x8 b, f32x4 c) {
  return __builtin_amdgcn_mfma_f32_16x16x32_bf16(a, b, c, 0, 0, 0);
}
DEV f32x16 mfma32(bf16x8 a, bf16x8 b, f32x16 c) {
  return __builtin_amdgcn_mfma_f32_32x32x16_bf16(a, b, c, 0, 0, 0);
}

DEV void gl_lds16(const unsigned short* g, unsigned short* l) {
  __builtin_amdgcn_global_load_lds(
      (const __attribute__((address_space(1))) unsigned int*)g,
      (__attribute__((address_space(3))) unsigned int*)l, 16, 0, 0);
}

// cvt two f32 pairs to packed bf16, then swap upper-half(a) <-> lower-half(b)
// across the wave. Yields two A-frag words (see layout notes in attn).
DEV void pk_swap(float a0, float a1, float b0, float b1,
                 unsigned int& w_lo, unsigned int& w_hi) {
  unsigned int a, b;
  asm("v_cvt_pk_bf16_f32 %0, %1, %2" : "=v"(a) : "v"(a0), "v"(a1));
  asm("v_cvt_pk_bf16_f32 %0, %1, %2" : "=v"(b) : "v"(b0), "v"(b1));
  asm("v_permlane32_swap_b32 %0, %1" : "+v"(a), "+v"(b));
  w_lo = a; w_hi = b;
}

// ---------------------------------------------------------------- prep
// blocks [0,8192): x f32 -> bf16 (1 float4/thread)
// blocks [8192,11264): Wqkv 1024x3072 transpose -> bf16 [3072][1024]
// blocks [11264,12288): Wproj 1024x1024 transpose -> bf16
__global__ __launch_bounds__(256) void prep(
    const float* __restrict__ x, unsigned short* __restrict__ xbf,
    const float* __restrict__ Wqkv, unsigned short* __restrict__ WqkvT,
    const float* __restrict__ Wproj, unsigned short* __restrict__ WprojT) {
  const int bid = blockIdx.x;
  if (bid < 8192) {
    const int i = (bid * 256 + threadIdx.x) * 4;
    const float4 v = *(const float4*)(x + i);
    ushort4 o;
    o.x = f2b(v.x); o.y = f2b(v.y); o.z = f2b(v.z); o.w = f2b(v.w);
    *(ushort4*)(xbf + i) = o;
    return;
  }
  __shared__ float tile[32][33];
  const float* in; unsigned short* out; int C, bx, by;
  if (bid < 11264) {
    const int bb = bid - 8192;
    bx = bb % 96; by = bb / 96; in = Wqkv; out = WqkvT; C = 3072;
  } else {
    const int bb = bid - 11264;
    bx = bb % 32; by = bb / 32; in = Wproj; out = WprojT; C = 1024;
  }
  const int R = 1024;
  const int tx = threadIdx.x & 31, ty = threadIdx.x >> 5;
  const int c0 = bx * 32, r0 = by * 32;
#pragma unroll
  for (int i = 0; i < 32; i += 8)
    tile[ty + i][tx] = in[(size_t)(r0 + ty + i) * C + (c0 + tx)];
  __syncthreads();
#pragma unroll
  for (int i = 0; i < 32; i += 8)
    out[(size_t)(c0 + ty + i) * R + (r0 + tx)] = f2b(tile[tx][ty + i]);
}

// ---------------------------------------------------------------- GEMM
// C[M,N] = A[M,K]*Bt[N,K]^T + bias. 128x128 tile, BK=32, 4 waves, m97-style
// global_load_lds staging.
// LDS swizzle (T2, rule 21): row r's physical 16B-chunk p holds logical
// chunk p ^ ((r>>1)&3); staged by inverse-swizzling the global source col
// (LDS dest stays linear, as gl_lds16 requires); frag reads use
// xg = g ^ ((ln>>1)&3)  (row&7 == ln&7 for all quads here).
// MODE 0: scatter bf16 to Q [b,h,t,d], K [b,h,t,d], V^T [b,h,d,t]
//         (Q prescaled 0.125*log2e; V^T quad stored as one ushort4).
// MODE 1: fp32 row-major output (final projection).
#define QSCALE 0.18033688f  // 0.125 * log2(e)
template <int MODE>
__global__ __launch_bounds__(256, 2) void gemm_bt(
    const unsigned short* __restrict__ A, const unsigned short* __restrict__ Bt,
    const float* __restrict__ bias, void* __restrict__ out_v,
    int M, int N, int K) {
  __shared__ __align__(16) unsigned short As[128 * 32];
  __shared__ __align__(16) unsigned short Bs[128 * 32];
  const int tid = threadIdx.x;
  const int w = tid >> 6, l = tid & 63, g = l >> 4, ln = l & 15;
  const int m0 = blockIdx.y * 128, n0 = blockIdx.x * 128;
  const int wm = (w & 1) * 64, wn = (w >> 1) * 64;

  f32x4 acc[4][4];
#pragma unroll
  for (int i = 0; i < 4; ++i)
#pragma unroll
    for (int j = 0; j < 4; ++j) acc[i][j] = (f32x4){0.f, 0.f, 0.f, 0.f};

  const unsigned short* Ab = A + (size_t)m0 * K;
  const unsigned short* Bb = Bt + (size_t)n0 * K;
  const int c0 = tid, c1 = tid + 256;
  const int ar0 = c0 >> 2, ar1 = c1 >> 2;
  // inverse-swizzled source chunk (involution: same XOR both sides)
  const int ak0 = (((c0 & 3) ^ ((ar0 >> 1) & 3))) * 8;
  const int ak1 = (((c1 & 3) ^ ((ar1 >> 1) & 3))) * 8;
  // swizzled read chunk for this lane's fragment rows (row&7 == ln&7)
  const int xg = (g ^ ((ln >> 1) & 3)) * 8;

  for (int k0 = 0; k0 < K; k0 += 32) {
    gl_lds16(Ab + (size_t)ar0 * K + k0 + ak0, &As[c0 * 8]);
    gl_lds16(Ab + (size_t)ar1 * K + k0 + ak1, &As[c1 * 8]);
    gl_lds16(Bb + (size_t)ar0 * K + k0 + ak0, &Bs[c0 * 8]);
    gl_lds16(Bb + (size_t)ar1 * K + k0 + ak1, &Bs[c1 * 8]);
    __syncthreads();
    bf16x8 af[4], bf[4];
#pragma unroll
    for (int mi = 0; mi < 4; ++mi)
      af[mi] = *(const bf16x8*)&As[(wm + mi * 16 + ln) * 32 + xg];
#pragma unroll
    for (int ni = 0; ni < 4; ++ni)
      bf[ni] = *(const bf16x8*)&Bs[(wn + ni * 16 + ln) * 32 + xg];
#pragma unroll
    for (int mi = 0; mi < 4; ++mi)
#pragma unroll
      for (int ni = 0; ni < 4; ++ni)
        acc[mi][ni] = mfma16(af[mi], bf[ni], acc[mi][ni]);
    __syncthreads();
  }

#pragma unroll
  for (int mi = 0; mi < 4; ++mi) {
#pragma unroll
    for (int ni = 0; ni < 4; ++ni) {
      const int row0 = m0 + wm + mi * 16 + 4 * g;
      const int col = n0 + wn + ni * 16 + ln;
      const float bv = bias[col];
      if (MODE == 0) {
        const int which = col >> 10;           // 0=Q 1=K 2=V
        const int h = (col >> 6) & 15;
        const int dd = col & 63;
        const int b = row0 >> 11, t0 = row0 & 2047;  // quad stays in one b
        if (which == 2) {
          // V^T [b,h,d,t]: 4 consecutive t -> one 8B store
          unsigned short* dst = (unsigned short*)out_v + (size_t)3 * 8388608u;
          ushort4 o;
          o.x = f2b(acc[mi][ni][0] + bv);
          o.y = f2b(acc[mi][ni][1] + bv);
          o.z = f2b(acc[mi][ni][2] + bv);
          o.w = f2b(acc[mi][ni][3] + bv);
          *(ushort4*)&dst[(((size_t)(b * 16 + h)) * 64 + dd) * 2048 + t0] = o;
        } else {
          unsigned short* dst = (unsigned short*)out_v + (size_t)which * 8388608u;
#pragma unroll
          for (int r = 0; r < 4; ++r) {
            float v = acc[mi][ni][r] + bv;
            if (which == 0) v *= QSCALE;
            dst[(((size_t)(b * 16 + h)) * 2048 + t0 + r) * 64 + dd] = f2b(v);
          }
        }
      } else {
#pragma unroll
        for (int r = 0; r < 4; ++r)
          ((float*)out_v)[(size_t)(row0 + r) * N + col] = acc[mi][ni][r] + bv;
      }
    }
  }
}

// ---------------------------------------------------------------- attention
// One block per (bh, 128-q tile); 4 waves, wave w owns q rows [32w, 32w+32).
// mfma 32x32x16. Q prescaled (log2 domain), no online max, deferred
// l-normalization.  [R9 body, verbatim -- passed 3x at ~83 us. FROZEN.]
// R18: XCD-chunked bijective block swizzle (index remap only): XCD k
// (= dispatch order % 8) gets 8 whole bh -> its L2 serves K/V for all 16
// q-tile blocks of those heads.
// SWAPPED QK^T: S^T = mfma32(K_frag, Q_frag) -> C/D col=l&31 is q, rows are
// keys at crow(r,lh)=(r&3)+8*(r>>2)+4*lh. Each lane owns P[q=l32][32 keys/nb].
// PV A-frag (m=q=l&31, k=lh*8+j) built in-register via pk_swap.
// Row-sums: os = mfma32(ap[ks], ones, os) -> os[r] = lsum(q=crow(r,lh)),
// identical layout to o[db][r]; epilogue needs no shuffles.
__global__ __launch_bounds__(256, 2) void attn(
    const unsigned short* __restrict__ Q, const unsigned short* __restrict__ K,
    const unsigned short* __restrict__ Vtg, unsigned short* __restrict__ Y) {
  __shared__ __align__(16) unsigned short Qs[128 * 72];
  __shared__ __align__(16) unsigned short Ks[64 * 72];     // [key][d]
  __shared__ __align__(16) unsigned short Vt[64 * 72];     // [d][key]

  const int tid = threadIdx.x;
  const int w = tid >> 6, l = tid & 63;
  const int l32 = l & 31, lh = l >> 5;       // half-wave select
  // XCD-chunked swizzle: wg in dispatch order, 1024 blocks, 1024%8==0
  const int wg = blockIdx.y * 16 + blockIdx.x;
  const int swz = (wg & 7) * 128 + (wg >> 3);
  const int bh = swz >> 4;
  const int q0 = (swz & 15) * 128;

  const unsigned short* Qb = Q + (size_t)bh * 131072;    // [t][d]
  const unsigned short* Kb = K + (size_t)bh * 131072;    // [t][d]
  const unsigned short* Vb = Vtg + (size_t)bh * 131072;  // [d][t]

  // stage Q: 128x64 bf16 -> stride-72 rows
#pragma unroll
  for (int i = 0; i < 4; ++i) {
    const int c = tid + i * 256;   // 1024 chunks
    u16x8 v = *(const u16x8*)(Qb + (size_t)q0 * 64 + c * 8);
    *(u16x8*)&Qs[(c >> 3) * 72 + (c & 7) * 8] = v;
  }
  __syncthreads();
  // hoist Q fragments (B-operand now; same (idx=l&31, k) mapping as A)
  bf16x8 aq[4];
#pragma unroll
  for (int kb = 0; kb < 4; ++kb)
    aq[kb] = *(const bf16x8*)&Qs[(w * 32 + l32) * 72 + kb * 16 + lh * 8];

  // ones B-frag (bf16 1.0 = 0x3F80) for the row-sum MFMA
  const short one_b = (short)0x3F80;
  const bf16x8 vones = (bf16x8){one_b, one_b, one_b, one_b,
                                one_b, one_b, one_b, one_b};

  f32x16 o[2], os;
#pragma unroll
  for (int db = 0; db < 2; ++db)
#pragma unroll
    for (int r = 0; r < 16; ++r) o[db][r] = 0.f;
#pragma unroll
  for (int r = 0; r < 16; ++r) os[r] = 0.f;

  for (int kt = 0; kt < 32; ++kt) {
    // stage K tile [key][d] and V tile [d][key] (V^T global)
#pragma unroll
    for (int i = 0; i < 2; ++i) {
      const int c = tid + i * 256;
      const int row = c >> 3, cc = (c & 7) * 8;
      u16x8 kv = *(const u16x8*)(Kb + (size_t)kt * 4096 + c * 8);
      u16x8 vv = *(const u16x8*)(Vb + (size_t)row * 2048 + kt * 64 + cc);
      *(u16x8*)&Ks[row * 72 + cc] = kv;
      *(u16x8*)&Vt[row * 72 + cc] = vv;
    }
    __syncthreads();

    // S^T = K Q^T : per wave 64k x 32q, two 32-key blocks (A=K, B=Q)
    f32x16 s[2];
#pragma unroll
    for (int nb = 0; nb < 2; ++nb) {
#pragma unroll
      for (int r = 0; r < 16; ++r) s[nb][r] = 0.f;
#pragma unroll
      for (int kb = 0; kb < 4; ++kb) {
        bf16x8 bk = *(const bf16x8*)&Ks[(nb * 32 + l32) * 72 + kb * 16 + lh * 8];
        s[nb] = mfma32(bk, aq[kb], s[nb]);
      }
    }

    // raw v_exp_f32 + in-register P->bf16 A-fragments (no LDS round-trip)
    bf16x8 ap[4];
#pragma unroll
    for (int nb = 0; nb < 2; ++nb) {
      float pe[16];
#pragma unroll
      for (int r = 0; r < 16; ++r)
        pe[r] = __builtin_amdgcn_exp2f(s[nb][r]);
      union { unsigned int wd[4]; bf16x8 v; } u0, u1;
      pk_swap(pe[0], pe[1], pe[4], pe[5], u0.wd[0], u0.wd[2]);
      pk_swap(pe[2], pe[3], pe[6], pe[7], u0.wd[1], u0.wd[3]);
      pk_swap(pe[8], pe[9], pe[12], pe[13], u1.wd[0], u1.wd[2]);
      pk_swap(pe[10], pe[11], pe[14], pe[15], u1.wd[1], u1.wd[3]);
      ap[2 * nb + 0] = u0.v;   // keys nb*32 + [0,16)
      ap[2 * nb + 1] = u1.v;   // keys nb*32 + [16,32)
    }

    // PV: A = P (in-register), B = V^T; row-sum on the MFMA pipe
#pragma unroll
    for (int ks = 0; ks < 4; ++ks) {
      os = mfma32(ap[ks], vones, os);
#pragma unroll
      for (int db = 0; db < 2; ++db) {
        bf16x8 bv = *(const bf16x8*)&Vt[(db * 32 + l32) * 72 + ks * 16 + lh * 8];
        o[db] = mfma32(ap[ks], bv, o[db]);
      }
    }
    __syncthreads();  // all waves done with Ks/Vt before next staging
  }

  // os[r] = sum over all keys of P[q=crow(r,lh)] -- same layout as o[db][r]
  float iv[16];
#pragma unroll
  for (int r = 0; r < 16; ++r) iv[r] = 1.f / os[r];

  // epilogue: y[b, t, h*64 + d]
  const int b = bh >> 4, h = bh & 15;
#pragma unroll
  for (int db = 0; db < 2; ++db)
#pragma unroll
    for (int r = 0; r < 16; ++r) {
      const int row = (r & 3) + 8 * (r >> 2) + 4 * lh;
      const int t = q0 + w * 32 + row;
      Y[(size_t)(b * 2048 + t) * 1024 + h * 64 + db * 32 + l32] =
          f2b(o[db][r] * iv[r]);
    }
}

// ---------------------------------------------------------------- launch
extern "C" void kernel_launch(void* const* d_in, const int* in_sizes, int n_in,
                              void* d_out, int out_size, void* d_ws, size_t ws_size,
                              hipStream_t stream) {
  const float* x     = (const float*)d_in[0];
  const float* Wqkv  = (const float*)d_in[1];
  const float* bqkv  = (const float*)d_in[2];
  const float* Wproj = (const float*)d_in[3];
  const float* bproj = (const float*)d_in[4];
  float* out = (float*)d_out;
  unsigned short* ws = (unsigned short*)d_ws;

  unsigned short* xbf    = ws;
  unsigned short* Yw     = xbf;  // alias: x dead after gemm_bt<0>
  unsigned short* WqkvT  = xbf + 8388608;
  unsigned short* WprojT = WqkvT + 3072 * 1024;
  unsigned short* Qw     = WprojT + 1024 * 1024;
  unsigned short* Kw     = Qw + 8388608;   // [b,h,t,d]
  unsigned short* Vw     = Kw + 8388608;   // (unused -- V written as V^T)
  unsigned short* Vtw    = Vw + 8388608;   // [b,h,d,t], written by gemm<0>
  (void)Vw;

  prep<<<12288, 256, 0, stream>>>(x, xbf, Wqkv, WqkvT, Wproj, WprojT);
  gemm_bt<0><<<dim3(24, 64), 256, 0, stream>>>(xbf, WqkvT, bqkv, Qw, 8192, 3072, 1024);
  attn<<<dim3(16, 64), 256, 0, stream>>>(Qw, Kw, Vtw, Yw);
  gemm_bt<1><<<dim3(8, 64), 256, 0, stream>>>(Yw, WprojT, bproj, out, 8192, 1024, 1024);
}

// Round 12
// 253.024 us; speedup vs baseline: 1.1688x; 1.0587x over previous
//
#include <hip/hip_runtime.h>

// MHSA. Inputs fp32, output fp32. B=4, T=2048, D=1024, H=16, hd=64.
// R19: gemm_bt latency attack (gemm0 = top dispatch, 83.3 us, all utils
// <30% -> barrier/vmcnt-drain bound at ~1800 cyc/step):
//  (a) BK 32->64: halves barrier+drain rounds (32->16). LDS 32 KB.
//      T2 swizzle re-derived for stride-128B rows: phys slot = logical ^
//      (row&7) (8 slots/row), inverse-swizzled global source col, read
//      slot (ks*4+g)^(ln&7) -- 8 lanes/4-bank group = b128 minimum.
//  (b) XCD-chunked bijective block swizzle on both gemms (R18's attn win:
//      FETCH 139->24.6 MB): A-panels become per-XCD L2 hits -> shorter
//      staging drains.
// attn body FROZEN (R9-verbatim + R18 swizzle); prep unchanged.

typedef __attribute__((ext_vector_type(8))) short bf16x8;
typedef __attribute__((ext_vector_type(8))) unsigned short u16x8;
typedef __attribute__((ext_vector_type(4))) float f32x4;
typedef __attribute__((ext_vector_type(16))) float f32x16;

#define DEV static __device__ __forceinline__

DEV unsigned short f2b(float f) {  // RTNE f32 -> bf16
  union { float f; unsigned int i; } v; v.f = f;
  unsigned int x = v.i;
  return (unsigned short)((x + 0x7FFFu + ((x >> 16) & 1u)) >> 16);
}

DEV f32x4 mfma16(bf16x8 a, bf16x8 b, f32x4 c) {
  return __builtin_amdgcn_mfma_f32_16x16x32_bf16(a, b, c, 0, 0, 0);
}
DEV f32x16 mfma32(bf16x8 a, bf16x8 b, f32x16 c) {
  return __builtin_amdgcn_mfma_f32_32x32x16_bf16(a, b, c, 0, 0, 0);
}

DEV void gl_lds16(const unsigned short* g, unsigned short* l) {
  __builtin_amdgcn_global_load_lds(
      (const __attribute__((address_space(1))) unsigned int*)g,
      (__attribute__((address_space(3))) unsigned int*)l, 16, 0, 0);
}

// cvt two f32 pairs to packed bf16, then swap upper-half(a) <-> lower-half(b)
// across the wave. Yields two A-frag words (see layout notes in attn).
DEV void pk_swap(float a0, float a1, float b0, float b1,
                 unsigned int& w_lo, unsigned int& w_hi) {
  unsigned int a, b;
  asm("v_cvt_pk_bf16_f32 %0, %1, %2" : "=v"(a) : "v"(a0), "v"(a1));
  asm("v_cvt_pk_bf16_f32 %0, %1, %2" : "=v"(b) : "v"(b0), "v"(b1));
  asm("v_permlane32_swap_b32 %0, %1" : "+v"(a), "+v"(b));
  w_lo = a; w_hi = b;
}

// ---------------------------------------------------------------- prep
// blocks [0,8192): x f32 -> bf16 (1 float4/thread)
// blocks [8192,11264): Wqkv 1024x3072 transpose -> bf16 [3072][1024]
// blocks [11264,12288): Wproj 1024x1024 transpose -> bf16
__global__ __launch_bounds__(256) void prep(
    const float* __restrict__ x, unsigned short* __restrict__ xbf,
    const float* __restrict__ Wqkv, unsigned short* __restrict__ WqkvT,
    const float* __restrict__ Wproj, unsigned short* __restrict__ WprojT) {
  const int bid = blockIdx.x;
  if (bid < 8192) {
    const int i = (bid * 256 + threadIdx.x) * 4;
    const float4 v = *(const float4*)(x + i);
    ushort4 o;
    o.x = f2b(v.x); o.y = f2b(v.y); o.z = f2b(v.z); o.w = f2b(v.w);
    *(ushort4*)(xbf + i) = o;
    return;
  }
  __shared__ float tile[32][33];
  const float* in; unsigned short* out; int C, bx, by;
  if (bid < 11264) {
    const int bb = bid - 8192;
    bx = bb % 96; by = bb / 96; in = Wqkv; out = WqkvT; C = 3072;
  } else {
    const int bb = bid - 11264;
    bx = bb % 32; by = bb / 32; in = Wproj; out = WprojT; C = 1024;
  }
  const int R = 1024;
  const int tx = threadIdx.x & 31, ty = threadIdx.x >> 5;
  const int c0 = bx * 32, r0 = by * 32;
#pragma unroll
  for (int i = 0; i < 32; i += 8)
    tile[ty + i][tx] = in[(size_t)(r0 + ty + i) * C + (c0 + tx)];
  __syncthreads();
#pragma unroll
  for (int i = 0; i < 32; i += 8)
    out[(size_t)(c0 + ty + i) * R + (r0 + tx)] = f2b(tile[tx][ty + i]);
}

// ---------------------------------------------------------------- GEMM
// C[M,N] = A[M,K]*Bt[N,K]^T + bias. 128x128 tile, BK=64, 4 waves,
// global_load_lds staging, 16 barrier rounds at K=1024.
// LDS swizzle (T2, rule 21): rows are 128 B (bank = slot*4, row-indep);
// physical 16B-slot s of row r holds logical slot s ^ (r&7); staged by
// inverse-swizzling the global source col (LDS dest linear for gl_lds16);
// frag read slot = (ks*4+g) ^ (ln&7)  (row&7 == ln&7 for all frag rows).
// XCD-chunked bijective block swizzle (nwg % 8 == 0).
// MODE 0: scatter bf16 to Q [b,h,t,d], K [b,h,t,d], V^T [b,h,d,t]
//         (Q prescaled 0.125*log2e; V^T quad stored as one ushort4).
// MODE 1: fp32 row-major output (final projection).
#define QSCALE 0.18033688f  // 0.125 * log2(e)
template <int MODE>
__global__ __launch_bounds__(256, 2) void gemm_bt(
    const unsigned short* __restrict__ A, const unsigned short* __restrict__ Bt,
    const float* __restrict__ bias, void* __restrict__ out_v,
    int M, int N, int K) {
  __shared__ __align__(16) unsigned short As[128 * 64];
  __shared__ __align__(16) unsigned short Bs[128 * 64];
  const int tid = threadIdx.x;
  const int w = tid >> 6, l = tid & 63, g = l >> 4, ln = l & 15;
  const int wm = (w & 1) * 64, wn = (w >> 1) * 64;

  // XCD-chunked bijective swizzle (nwg % 8 == 0 for both gemms)
  const int nwg = gridDim.x * gridDim.y;
  int wg = blockIdx.y * gridDim.x + blockIdx.x;
  wg = (wg & 7) * (nwg >> 3) + (wg >> 3);
  const int m0 = (wg / gridDim.x) * 128, n0 = (wg % gridDim.x) * 128;

  f32x4 acc[4][4];
#pragma unroll
  for (int i = 0; i < 4; ++i)
#pragma unroll
    for (int j = 0; j < 4; ++j) acc[i][j] = (f32x4){0.f, 0.f, 0.f, 0.f};

  const unsigned short* Ab = A + (size_t)m0 * K;
  const unsigned short* Bb = Bt + (size_t)n0 * K;
  // read slot XOR for this lane's fragment rows (row&7 == ln&7)
  const int lx = ln & 7;

  for (int k0 = 0; k0 < K; k0 += 64) {
#pragma unroll
    for (int i = 0; i < 4; ++i) {
      const int ch = tid + i * 256;          // 1024 chunks of 8 elems
      const int ar = ch >> 3, s = ch & 7;
      const int sc = (s ^ (ar & 7)) * 8;     // inverse-swizzled source col
      gl_lds16(Ab + (size_t)ar * K + k0 + sc, &As[ch * 8]);
      gl_lds16(Bb + (size_t)ar * K + k0 + sc, &Bs[ch * 8]);
    }
    __syncthreads();
#pragma unroll
    for (int ks = 0; ks < 2; ++ks) {
      const int so = ((ks * 4 + g) ^ lx) * 8;
      bf16x8 af[4], bf[4];
#pragma unroll
      for (int mi = 0; mi < 4; ++mi)
        af[mi] = *(const bf16x8*)&As[(wm + mi * 16 + ln) * 64 + so];
#pragma unroll
      for (int ni = 0; ni < 4; ++ni)
        bf[ni] = *(const bf16x8*)&Bs[(wn + ni * 16 + ln) * 64 + so];
#pragma unroll
      for (int mi = 0; mi < 4; ++mi)
#pragma unroll
        for (int ni = 0; ni < 4; ++ni)
          acc[mi][ni] = mfma16(af[mi], bf[ni], acc[mi][ni]);
    }
    __syncthreads();
  }

#pragma unroll
  for (int mi = 0; mi < 4; ++mi) {
#pragma unroll
    for (int ni = 0; ni < 4; ++ni) {
      const int row0 = m0 + wm + mi * 16 + 4 * g;
      const int col = n0 + wn + ni * 16 + ln;
      const float bv = bias[col];
      if (MODE == 0) {
        const int which = col >> 10;           // 0=Q 1=K 2=V
        const int h = (col >> 6) & 15;
        const int dd = col & 63;
        const int b = row0 >> 11, t0 = row0 & 2047;  // quad stays in one b
        if (which == 2) {
          // V^T [b,h,d,t]: 4 consecutive t -> one 8B store
          unsigned short* dst = (unsigned short*)out_v + (size_t)3 * 8388608u;
          ushort4 o;
          o.x = f2b(acc[mi][ni][0] + bv);
          o.y = f2b(acc[mi][ni][1] + bv);
          o.z = f2b(acc[mi][ni][2] + bv);
          o.w = f2b(acc[mi][ni][3] + bv);
          *(ushort4*)&dst[(((size_t)(b * 16 + h)) * 64 + dd) * 2048 + t0] = o;
        } else {
          unsigned short* dst = (unsigned short*)out_v + (size_t)which * 8388608u;
#pragma unroll
          for (int r = 0; r < 4; ++r) {
            float v = acc[mi][ni][r] + bv;
            if (which == 0) v *= QSCALE;
            dst[(((size_t)(b * 16 + h)) * 2048 + t0 + r) * 64 + dd] = f2b(v);
          }
        }
      } else {
#pragma unroll
        for (int r = 0; r < 4; ++r)
          ((float*)out_v)[(size_t)(row0 + r) * N + col] = acc[mi][ni][r] + bv;
      }
    }
  }
}

// ---------------------------------------------------------------- attention
// One block per (bh, 128-q tile); 4 waves, wave w owns q rows [32w, 32w+32).
// mfma 32x32x16. Q prescaled (log2 domain), no online max, deferred
// l-normalization.  [R9 body, verbatim -- passed 4x. FROZEN.]
// XCD-chunked bijective block swizzle (R18): XCD k gets 8 whole bh.
// SWAPPED QK^T: S^T = mfma32(K_frag, Q_frag) -> C/D col=l&31 is q, rows are
// keys at crow(r,lh)=(r&3)+8*(r>>2)+4*lh. Each lane owns P[q=l32][32 keys/nb].
// PV A-frag (m=q=l&31, k=lh*8+j) built in-register via pk_swap.
// Row-sums: os = mfma32(ap[ks], ones, os) -> os[r] = lsum(q=crow(r,lh)),
// identical layout to o[db][r]; epilogue needs no shuffles.
__global__ __launch_bounds__(256, 2) void attn(
    const unsigned short* __restrict__ Q, const unsigned short* __restrict__ K,
    const unsigned short* __restrict__ Vtg, unsigned short* __restrict__ Y) {
  __shared__ __align__(16) unsigned short Qs[128 * 72];
  __shared__ __align__(16) unsigned short Ks[64 * 72];     // [key][d]
  __shared__ __align__(16) unsigned short Vt[64 * 72];     // [d][key]

  const int tid = threadIdx.x;
  const int w = tid >> 6, l = tid & 63;
  const int l32 = l & 31, lh = l >> 5;       // half-wave select
  // XCD-chunked swizzle: wg in dispatch order, 1024 blocks, 1024%8==0
  const int wg = blockIdx.y * 16 + blockIdx.x;
  const int swz = (wg & 7) * 128 + (wg >> 3);
  const int bh = swz >> 4;
  const int q0 = (swz & 15) * 128;

  const unsigned short* Qb = Q + (size_t)bh * 131072;    // [t][d]
  const unsigned short* Kb = K + (size_t)bh * 131072;    // [t][d]
  const unsigned short* Vb = Vtg + (size_t)bh * 131072;  // [d][t]

  // stage Q: 128x64 bf16 -> stride-72 rows
#pragma unroll
  for (int i = 0; i < 4; ++i) {
    const int c = tid + i * 256;   // 1024 chunks
    u16x8 v = *(const u16x8*)(Qb + (size_t)q0 * 64 + c * 8);
    *(u16x8*)&Qs[(c >> 3) * 72 + (c & 7) * 8] = v;
  }
  __syncthreads();
  // hoist Q fragments (B-operand now; same (idx=l&31, k) mapping as A)
  bf16x8 aq[4];
#pragma unroll
  for (int kb = 0; kb < 4; ++kb)
    aq[kb] = *(const bf16x8*)&Qs[(w * 32 + l32) * 72 + kb * 16 + lh * 8];

  // ones B-frag (bf16 1.0 = 0x3F80) for the row-sum MFMA
  const short one_b = (short)0x3F80;
  const bf16x8 vones = (bf16x8){one_b, one_b, one_b, one_b,
                                one_b, one_b, one_b, one_b};

  f32x16 o[2], os;
#pragma unroll
  for (int db = 0; db < 2; ++db)
#pragma unroll
    for (int r = 0; r < 16; ++r) o[db][r] = 0.f;
#pragma unroll
  for (int r = 0; r < 16; ++r) os[r] = 0.f;

  for (int kt = 0; kt < 32; ++kt) {
    // stage K tile [key][d] and V tile [d][key] (V^T global)
#pragma unroll
    for (int i = 0; i < 2; ++i) {
      const int c = tid + i * 256;
      const int row = c >> 3, cc = (c & 7) * 8;
      u16x8 kv = *(const u16x8*)(Kb + (size_t)kt * 4096 + c * 8);
      u16x8 vv = *(const u16x8*)(Vb + (size_t)row * 2048 + kt * 64 + cc);
      *(u16x8*)&Ks[row * 72 + cc] = kv;
      *(u16x8*)&Vt[row * 72 + cc] = vv;
    }
    __syncthreads();

    // S^T = K Q^T : per wave 64k x 32q, two 32-key blocks (A=K, B=Q)
    f32x16 s[2];
#pragma unroll
    for (int nb = 0; nb < 2; ++nb) {
#pragma unroll
      for (int r = 0; r < 16; ++r) s[nb][r] = 0.f;
#pragma unroll
      for (int kb = 0; kb < 4; ++kb) {
        bf16x8 bk = *(const bf16x8*)&Ks[(nb * 32 + l32) * 72 + kb * 16 + lh * 8];
        s[nb] = mfma32(bk, aq[kb], s[nb]);
      }
    }

    // raw v_exp_f32 + in-register P->bf16 A-fragments (no LDS round-trip)
    bf16x8 ap[4];
#pragma unroll
    for (int nb = 0; nb < 2; ++nb) {
      float pe[16];
#pragma unroll
      for (int r = 0; r < 16; ++r)
        pe[r] = __builtin_amdgcn_exp2f(s[nb][r]);
      union { unsigned int wd[4]; bf16x8 v; } u0, u1;
      pk_swap(pe[0], pe[1], pe[4], pe[5], u0.wd[0], u0.wd[2]);
      pk_swap(pe[2], pe[3], pe[6], pe[7], u0.wd[1], u0.wd[3]);
      pk_swap(pe[8], pe[9], pe[12], pe[13], u1.wd[0], u1.wd[2]);
      pk_swap(pe[10], pe[11], pe[14], pe[15], u1.wd[1], u1.wd[3]);
      ap[2 * nb + 0] = u0.v;   // keys nb*32 + [0,16)
      ap[2 * nb + 1] = u1.v;   // keys nb*32 + [16,32)
    }

    // PV: A = P (in-register), B = V^T; row-sum on the MFMA pipe
#pragma unroll
    for (int ks = 0; ks < 4; ++ks) {
      os = mfma32(ap[ks], vones, os);
#pragma unroll
      for (int db = 0; db < 2; ++db) {
        bf16x8 bv = *(const bf16x8*)&Vt[(db * 32 + l32) * 72 + ks * 16 + lh * 8];
        o[db] = mfma32(ap[ks], bv, o[db]);
      }
    }
    __syncthreads();  // all waves done with Ks/Vt before next staging
  }

  // os[r] = sum over all keys of P[q=crow(r,lh)] -- same layout as o[db][r]
  float iv[16];
#pragma unroll
  for (int r = 0; r < 16; ++r) iv[r] = 1.f / os[r];

  // epilogue: y[b, t, h*64 + d]
  const int b = bh >> 4, h = bh & 15;
#pragma unroll
  for (int db = 0; db < 2; ++db)
#pragma unroll
    for (int r = 0; r < 16; ++r) {
      const int row = (r & 3) + 8 * (r >> 2) + 4 * lh;
      const int t = q0 + w * 32 + row;
      Y[(size_t)(b * 2048 + t) * 1024 + h * 64 + db * 32 + l32] =
          f2b(o[db][r] * iv[r]);
    }
}

// ---------------------------------------------------------------- launch
extern "C" void kernel_launch(void* const* d_in, const int* in_sizes, int n_in,
                              void* d_out, int out_size, void* d_ws, size_t ws_size,
                              hipStream_t stream) {
  const float* x     = (const float*)d_in[0];
  const float* Wqkv  = (const float*)d_in[1];
  const float* bqkv  = (const float*)d_in[2];
  const float* Wproj = (const float*)d_in[3];
  const float* bproj = (const float*)d_in[4];
  float* out = (float*)d_out;
  unsigned short* ws = (unsigned short*)d_ws;

  unsigned short* xbf    = ws;
  unsigned short* Yw     = xbf;  // alias: x dead after gemm_bt<0>
  unsigned short* WqkvT  = xbf + 8388608;
  unsigned short* WprojT = WqkvT + 3072 * 1024;
  unsigned short* Qw     = WprojT + 1024 * 1024;
  unsigned short* Kw     = Qw + 8388608;   // [b,h,t,d]
  unsigned short* Vw     = Kw + 8388608;   // (unused -- V written as V^T)
  unsigned short* Vtw    = Vw + 8388608;   // [b,h,d,t], written by gemm<0>
  (void)Vw; (void)Kw;

  prep<<<12288, 256, 0, stream>>>(x, xbf, Wqkv, WqkvT, Wproj, WprojT);
  gemm_bt<0><<<dim3(24, 64), 256, 0, stream>>>(xbf, WqkvT, bqkv, Qw, 8192, 3072, 1024);
  attn<<<dim3(16, 64), 256, 0, stream>>>(Qw, Qw + 8388608, Vtw, Yw);
  gemm_bt<1><<<dim3(8, 64), 256, 0, stream>>>(Yw, WprojT, bproj, out, 8192, 1024, 1024);
}

// Round 13
// 246.809 us; speedup vs baseline: 1.1982x; 1.0252x over previous
//
#include <hip/hip_runtime.h>

// MHSA. Inputs fp32, output fp32. B=4, T=2048, D=1024, H=16, hd=64.
// R20: (a) attn: ones-MFMA row-sum (4 of 20 mfma32/kt = +20% matrix-pipe
//      work) -> R8-proven per-lane VALU lsum (lsp[r&3] += pe[r], 4-way ILP)
//      + shfl_xor(32) combine + 16 one-time shuffles into the C/D layout.
//      Register-only; frozen staging/sync untouched (softmax-register edits
//      passed 3/3; staging edits failed 4/4).
//      (b) gemm<1> (tail kernel, 512 blocks = 2/CU latency-starved) ->
//      gemm_proj 64x128 tile: 1024 blocks = 4/CU, 24 KB LDS, per-block
//      chain halved; same T2 swizzle algebra; XCD chunk = 2+2 MB per L2.
// gemm_bt<0> keeps R19 (BK=64 + T2 + XCD). prep unchanged.

typedef __attribute__((ext_vector_type(8))) short bf16x8;
typedef __attribute__((ext_vector_type(8))) unsigned short u16x8;
typedef __attribute__((ext_vector_type(4))) float f32x4;
typedef __attribute__((ext_vector_type(16))) float f32x16;

#define DEV static __device__ __forceinline__

DEV unsigned short f2b(float f) {  // RTNE f32 -> bf16
  union { float f; unsigned int i; } v; v.f = f;
  unsigned int x = v.i;
  return (unsigned short)((x + 0x7FFFu + ((x >> 16) & 1u)) >> 16);
}

DEV f32x4 mfma16(bf16x8 a, bf16x8 b, f32x4 c) {
  return __builtin_amdgcn_mfma_f32_16x16x32_bf16(a, b, c, 0, 0, 0);
}
DEV f32x16 mfma32(bf16x8 a, bf16x8 b, f32x16 c) {
  return __builtin_amdgcn_mfma_f32_32x32x16_bf16(a, b, c, 0, 0, 0);
}

DEV void gl_lds16(const unsigned short* g, unsigned short* l) {
  __builtin_amdgcn_global_load_lds(
      (const __attribute__((address_space(1))) unsigned int*)g,
      (__attribute__((address_space(3))) unsigned int*)l, 16, 0, 0);
}

// cvt two f32 pairs to packed bf16, then swap upper-half(a) <-> lower-half(b)
// across the wave. Yields two A-frag words (see layout notes in attn).
DEV void pk_swap(float a0, float a1, float b0, float b1,
                 unsigned int& w_lo, unsigned int& w_hi) {
  unsigned int a, b;
  asm("v_cvt_pk_bf16_f32 %0, %1, %2" : "=v"(a) : "v"(a0), "v"(a1));
  asm("v_cvt_pk_bf16_f32 %0, %1, %2" : "=v"(b) : "v"(b0), "v"(b1));
  asm("v_permlane32_swap_b32 %0, %1" : "+v"(a), "+v"(b));
  w_lo = a; w_hi = b;
}

// ---------------------------------------------------------------- prep
// blocks [0,8192): x f32 -> bf16 (1 float4/thread)
// blocks [8192,11264): Wqkv 1024x3072 transpose -> bf16 [3072][1024]
// blocks [11264,12288): Wproj 1024x1024 transpose -> bf16
__global__ __launch_bounds__(256) void prep(
    const float* __restrict__ x, unsigned short* __restrict__ xbf,
    const float* __restrict__ Wqkv, unsigned short* __restrict__ WqkvT,
    const float* __restrict__ Wproj, unsigned short* __restrict__ WprojT) {
  const int bid = blockIdx.x;
  if (bid < 8192) {
    const int i = (bid * 256 + threadIdx.x) * 4;
    const float4 v = *(const float4*)(x + i);
    ushort4 o;
    o.x = f2b(v.x); o.y = f2b(v.y); o.z = f2b(v.z); o.w = f2b(v.w);
    *(ushort4*)(xbf + i) = o;
    return;
  }
  __shared__ float tile[32][33];
  const float* in; unsigned short* out; int C, bx, by;
  if (bid < 11264) {
    const int bb = bid - 8192;
    bx = bb % 96; by = bb / 96; in = Wqkv; out = WqkvT; C = 3072;
  } else {
    const int bb = bid - 11264;
    bx = bb % 32; by = bb / 32; in = Wproj; out = WprojT; C = 1024;
  }
  const int R = 1024;
  const int tx = threadIdx.x & 31, ty = threadIdx.x >> 5;
  const int c0 = bx * 32, r0 = by * 32;
#pragma unroll
  for (int i = 0; i < 32; i += 8)
    tile[ty + i][tx] = in[(size_t)(r0 + ty + i) * C + (c0 + tx)];
  __syncthreads();
#pragma unroll
  for (int i = 0; i < 32; i += 8)
    out[(size_t)(c0 + ty + i) * R + (r0 + tx)] = f2b(tile[tx][ty + i]);
}

// ---------------------------------------------------------------- GEMM QKV
// C[M,N] = A[M,K]*Bt[N,K]^T + bias. 128x128 tile, BK=64, 4 waves,
// global_load_lds staging, 16 barrier rounds at K=1024.
// LDS swizzle (T2, rule 21): rows are 128 B; physical 16B-slot s of row r
// holds logical slot s ^ (r&7); staged via inverse-swizzled global source
// col (LDS dest linear); read slot (ks*4+g) ^ (ln&7).
// XCD-chunked bijective block swizzle (nwg % 8 == 0).
// Scatter bf16 to Q [b,h,t,d], K [b,h,t,d], V^T [b,h,d,t]
// (Q prescaled 0.125*log2e; V^T quad stored as one ushort4).
#define QSCALE 0.18033688f  // 0.125 * log2(e)
__global__ __launch_bounds__(256, 2) void gemm_qkv(
    const unsigned short* __restrict__ A, const unsigned short* __restrict__ Bt,
    const float* __restrict__ bias, unsigned short* __restrict__ out,
    int M, int N, int K) {
  __shared__ __align__(16) unsigned short As[128 * 64];
  __shared__ __align__(16) unsigned short Bs[128 * 64];
  const int tid = threadIdx.x;
  const int w = tid >> 6, l = tid & 63, g = l >> 4, ln = l & 15;
  const int wm = (w & 1) * 64, wn = (w >> 1) * 64;

  const int nwg = gridDim.x * gridDim.y;
  int wg = blockIdx.y * gridDim.x + blockIdx.x;
  wg = (wg & 7) * (nwg >> 3) + (wg >> 3);
  const int m0 = (wg / gridDim.x) * 128, n0 = (wg % gridDim.x) * 128;

  f32x4 acc[4][4];
#pragma unroll
  for (int i = 0; i < 4; ++i)
#pragma unroll
    for (int j = 0; j < 4; ++j) acc[i][j] = (f32x4){0.f, 0.f, 0.f, 0.f};

  const unsigned short* Ab = A + (size_t)m0 * K;
  const unsigned short* Bb = Bt + (size_t)n0 * K;
  const int lx = ln & 7;

  for (int k0 = 0; k0 < K; k0 += 64) {
#pragma unroll
    for (int i = 0; i < 4; ++i) {
      const int ch = tid + i * 256;          // 1024 chunks of 8 elems
      const int ar = ch >> 3, s = ch & 7;
      const int sc = (s ^ (ar & 7)) * 8;     // inverse-swizzled source col
      gl_lds16(Ab + (size_t)ar * K + k0 + sc, &As[ch * 8]);
      gl_lds16(Bb + (size_t)ar * K + k0 + sc, &Bs[ch * 8]);
    }
    __syncthreads();
#pragma unroll
    for (int ks = 0; ks < 2; ++ks) {
      const int so = ((ks * 4 + g) ^ lx) * 8;
      bf16x8 af[4], bf[4];
#pragma unroll
      for (int mi = 0; mi < 4; ++mi)
        af[mi] = *(const bf16x8*)&As[(wm + mi * 16 + ln) * 64 + so];
#pragma unroll
      for (int ni = 0; ni < 4; ++ni)
        bf[ni] = *(const bf16x8*)&Bs[(wn + ni * 16 + ln) * 64 + so];
#pragma unroll
      for (int mi = 0; mi < 4; ++mi)
#pragma unroll
        for (int ni = 0; ni < 4; ++ni)
          acc[mi][ni] = mfma16(af[mi], bf[ni], acc[mi][ni]);
    }
    __syncthreads();
  }

#pragma unroll
  for (int mi = 0; mi < 4; ++mi) {
#pragma unroll
    for (int ni = 0; ni < 4; ++ni) {
      const int row0 = m0 + wm + mi * 16 + 4 * g;
      const int col = n0 + wn + ni * 16 + ln;
      const float bv = bias[col];
      const int which = col >> 10;           // 0=Q 1=K 2=V
      const int h = (col >> 6) & 15;
      const int dd = col & 63;
      const int b = row0 >> 11, t0 = row0 & 2047;  // quad stays in one b
      if (which == 2) {
        // V^T [b,h,d,t]: 4 consecutive t -> one 8B store
        unsigned short* dst = out + (size_t)3 * 8388608u;
        ushort4 o;
        o.x = f2b(acc[mi][ni][0] + bv);
        o.y = f2b(acc[mi][ni][1] + bv);
        o.z = f2b(acc[mi][ni][2] + bv);
        o.w = f2b(acc[mi][ni][3] + bv);
        *(ushort4*)&dst[(((size_t)(b * 16 + h)) * 64 + dd) * 2048 + t0] = o;
      } else {
        unsigned short* dst = out + (size_t)which * 8388608u;
#pragma unroll
        for (int r = 0; r < 4; ++r) {
          float v = acc[mi][ni][r] + bv;
          if (which == 0) v *= QSCALE;
          dst[(((size_t)(b * 16 + h)) * 2048 + t0 + r) * 64 + dd] = f2b(v);
        }
      }
    }
  }
}

// ---------------------------------------------------------------- GEMM proj
// C[M,N] = A[M,K]*Bt[N,K]^T + bias, fp32 out. 64x128 tile, BK=64, 4 waves
// (each 32Mx64N), 1024 blocks = 4/CU (tail kernel: latency matters).
// Same T2 swizzle (A rows 64, B rows 128; row&7 == ln&7 both). XCD chunk:
// each XCD gets 16 M-rows x all N -> A 2 MB + B 2 MB, fits its L2.
__global__ __launch_bounds__(256, 2) void gemm_proj(
    const unsigned short* __restrict__ A, const unsigned short* __restrict__ Bt,
    const float* __restrict__ bias, float* __restrict__ out,
    int M, int N, int K) {
  __shared__ __align__(16) unsigned short As[64 * 64];
  __shared__ __align__(16) unsigned short Bs[128 * 64];
  const int tid = threadIdx.x;
  const int w = tid >> 6, l = tid & 63, g = l >> 4, ln = l & 15;
  const int wm = (w & 1) * 32, wn = (w >> 1) * 64;

  const int nwg = gridDim.x * gridDim.y;   // 8 * 128 = 1024
  int wg = blockIdx.y * gridDim.x + blockIdx.x;
  wg = (wg & 7) * (nwg >> 3) + (wg >> 3);
  const int m0 = (wg / gridDim.x) * 64, n0 = (wg % gridDim.x) * 128;

  f32x4 acc[2][4];
#pragma unroll
  for (int i = 0; i < 2; ++i)
#pragma unroll
    for (int j = 0; j < 4; ++j) acc[i][j] = (f32x4){0.f, 0.f, 0.f, 0.f};

  const unsigned short* Ab = A + (size_t)m0 * K;
  const unsigned short* Bb = Bt + (size_t)n0 * K;
  const int lx = ln & 7;

  for (int k0 = 0; k0 < K; k0 += 64) {
#pragma unroll
    for (int i = 0; i < 2; ++i) {           // A: 512 chunks
      const int ch = tid + i * 256;
      const int ar = ch >> 3, s = ch & 7;
      const int sc = (s ^ (ar & 7)) * 8;
      gl_lds16(Ab + (size_t)ar * K + k0 + sc, &As[ch * 8]);
    }
#pragma unroll
    for (int i = 0; i < 4; ++i) {           // B: 1024 chunks
      const int ch = tid + i * 256;
      const int br = ch >> 3, s = ch & 7;
      const int sc = (s ^ (br & 7)) * 8;
      gl_lds16(Bb + (size_t)br * K + k0 + sc, &Bs[ch * 8]);
    }
    __syncthreads();
#pragma unroll
    for (int ks = 0; ks < 2; ++ks) {
      const int so = ((ks * 4 + g) ^ lx) * 8;
      bf16x8 af[2], bf[4];
#pragma unroll
      for (int mi = 0; mi < 2; ++mi)
        af[mi] = *(const bf16x8*)&As[(wm + mi * 16 + ln) * 64 + so];
#pragma unroll
      for (int ni = 0; ni < 4; ++ni)
        bf[ni] = *(const bf16x8*)&Bs[(wn + ni * 16 + ln) * 64 + so];
#pragma unroll
      for (int mi = 0; mi < 2; ++mi)
#pragma unroll
        for (int ni = 0; ni < 4; ++ni)
          acc[mi][ni] = mfma16(af[mi], bf[ni], acc[mi][ni]);
    }
    __syncthreads();
  }

#pragma unroll
  for (int mi = 0; mi < 2; ++mi) {
#pragma unroll
    for (int ni = 0; ni < 4; ++ni) {
      const int row0 = m0 + wm + mi * 16 + 4 * g;
      const int col = n0 + wn + ni * 16 + ln;
      const float bv = bias[col];
#pragma unroll
      for (int r = 0; r < 4; ++r)
        out[(size_t)(row0 + r) * N + col] = acc[mi][ni][r] + bv;
    }
  }
}

// ---------------------------------------------------------------- attention
// One block per (bh, 128-q tile); 4 waves, wave w owns q rows [32w, 32w+32).
// mfma 32x32x16. Q prescaled (log2 domain), no online max, deferred
// l-normalization.  [Staging/sync structure FROZEN at R9 (passed 5x).]
// R20: row-sum moved off the MFMA pipe (was +20% matrix work): per-lane
// lsp[r&3] += pe[r] (4-way ILP VALU), shfl_xor(32) combine, 16 one-time
// shuffles redistribute 1/l into the C/D layout (exact R8 epilogue).
// XCD-chunked bijective block swizzle (R18): XCD k gets 8 whole bh.
// SWAPPED QK^T: S^T = mfma32(K_frag, Q_frag) -> C/D col=l&31 is q, rows are
// keys at crow(r,lh)=(r&3)+8*(r>>2)+4*lh. Each lane owns P[q=l32][32 keys/nb].
// PV A-frag (m=q=l&31, k=lh*8+j) built in-register via pk_swap.
__global__ __launch_bounds__(256, 2) void attn(
    const unsigned short* __restrict__ Q, const unsigned short* __restrict__ K,
    const unsigned short* __restrict__ Vtg, unsigned short* __restrict__ Y) {
  __shared__ __align__(16) unsigned short Qs[128 * 72];
  __shared__ __align__(16) unsigned short Ks[64 * 72];     // [key][d]
  __shared__ __align__(16) unsigned short Vt[64 * 72];     // [d][key]

  const int tid = threadIdx.x;
  const int w = tid >> 6, l = tid & 63;
  const int l32 = l & 31, lh = l >> 5;       // half-wave select
  // XCD-chunked swizzle: wg in dispatch order, 1024 blocks, 1024%8==0
  const int wg = blockIdx.y * 16 + blockIdx.x;
  const int swz = (wg & 7) * 128 + (wg >> 3);
  const int bh = swz >> 4;
  const int q0 = (swz & 15) * 128;

  const unsigned short* Qb = Q + (size_t)bh * 131072;    // [t][d]
  const unsigned short* Kb = K + (size_t)bh * 131072;    // [t][d]
  const unsigned short* Vb = Vtg + (size_t)bh * 131072;  // [d][t]

  // stage Q: 128x64 bf16 -> stride-72 rows
#pragma unroll
  for (int i = 0; i < 4; ++i) {
    const int c = tid + i * 256;   // 1024 chunks
    u16x8 v = *(const u16x8*)(Qb + (size_t)q0 * 64 + c * 8);
    *(u16x8*)&Qs[(c >> 3) * 72 + (c & 7) * 8] = v;
  }
  __syncthreads();
  // hoist Q fragments (B-operand now; same (idx=l&31, k) mapping as A)
  bf16x8 aq[4];
#pragma unroll
  for (int kb = 0; kb < 4; ++kb)
    aq[kb] = *(const bf16x8*)&Qs[(w * 32 + l32) * 72 + kb * 16 + lh * 8];

  f32x16 o[2];
#pragma unroll
  for (int db = 0; db < 2; ++db)
#pragma unroll
    for (int r = 0; r < 16; ++r) o[db][r] = 0.f;
  float lsp[4] = {0.f, 0.f, 0.f, 0.f};  // 4-way ILP row-sum partials

  for (int kt = 0; kt < 32; ++kt) {
    // stage K tile [key][d] and V tile [d][key] (V^T global)
#pragma unroll
    for (int i = 0; i < 2; ++i) {
      const int c = tid + i * 256;
      const int row = c >> 3, cc = (c & 7) * 8;
      u16x8 kv = *(const u16x8*)(Kb + (size_t)kt * 4096 + c * 8);
      u16x8 vv = *(const u16x8*)(Vb + (size_t)row * 2048 + kt * 64 + cc);
      *(u16x8*)&Ks[row * 72 + cc] = kv;
      *(u16x8*)&Vt[row * 72 + cc] = vv;
    }
    __syncthreads();

    // S^T = K Q^T : per wave 64k x 32q, two 32-key blocks (A=K, B=Q)
    f32x16 s[2];
#pragma unroll
    for (int nb = 0; nb < 2; ++nb) {
#pragma unroll
      for (int r = 0; r < 16; ++r) s[nb][r] = 0.f;
#pragma unroll
      for (int kb = 0; kb < 4; ++kb) {
        bf16x8 bk = *(const bf16x8*)&Ks[(nb * 32 + l32) * 72 + kb * 16 + lh * 8];
        s[nb] = mfma32(bk, aq[kb], s[nb]);
      }
    }

    // raw v_exp_f32 + VALU row-sum + in-register P->bf16 A-fragments
    bf16x8 ap[4];
#pragma unroll
    for (int nb = 0; nb < 2; ++nb) {
      float pe[16];
#pragma unroll
      for (int r = 0; r < 16; ++r) {
        pe[r] = __builtin_amdgcn_exp2f(s[nb][r]);
        lsp[r & 3] += pe[r];
      }
      union { unsigned int wd[4]; bf16x8 v; } u0, u1;
      pk_swap(pe[0], pe[1], pe[4], pe[5], u0.wd[0], u0.wd[2]);
      pk_swap(pe[2], pe[3], pe[6], pe[7], u0.wd[1], u0.wd[3]);
      pk_swap(pe[8], pe[9], pe[12], pe[13], u1.wd[0], u1.wd[2]);
      pk_swap(pe[10], pe[11], pe[14], pe[15], u1.wd[1], u1.wd[3]);
      ap[2 * nb + 0] = u0.v;   // keys nb*32 + [0,16)
      ap[2 * nb + 1] = u1.v;   // keys nb*32 + [16,32)
    }

    // PV: A = P (in-register), B = V^T (16 useful mfma32/kt, no ones-MFMA)
#pragma unroll
    for (int ks = 0; ks < 4; ++ks)
#pragma unroll
      for (int db = 0; db < 2; ++db) {
        bf16x8 bv = *(const bf16x8*)&Vt[(db * 32 + l32) * 72 + ks * 16 + lh * 8];
        o[db] = mfma32(ap[ks], bv, o[db]);
      }
    __syncthreads();  // all waves done with Ks/Vt before next staging
  }

  // per-lane lsum covers this lane's key set for q=l32; partner half at l^32
  float lsum = (lsp[0] + lsp[1]) + (lsp[2] + lsp[3]);
  lsum += __shfl_xor(lsum, 32, 64);
  // redistribute 1/l to the C/D layout (row r lives at lane crow(r,lh))
  float iv[16];
#pragma unroll
  for (int r = 0; r < 16; ++r) {
    const int row = (r & 3) + 8 * (r >> 2) + 4 * lh;
    iv[r] = 1.f / __shfl(lsum, row, 64);
  }

  // epilogue: y[b, t, h*64 + d]
  const int b = bh >> 4, h = bh & 15;
#pragma unroll
  for (int db = 0; db < 2; ++db)
#pragma unroll
    for (int r = 0; r < 16; ++r) {
      const int row = (r & 3) + 8 * (r >> 2) + 4 * lh;
      const int t = q0 + w * 32 + row;
      Y[(size_t)(b * 2048 + t) * 1024 + h * 64 + db * 32 + l32] =
          f2b(o[db][r] * iv[r]);
    }
}

// ---------------------------------------------------------------- launch
extern "C" void kernel_launch(void* const* d_in, const int* in_sizes, int n_in,
                              void* d_out, int out_size, void* d_ws, size_t ws_size,
                              hipStream_t stream) {
  const float* x     = (const float*)d_in[0];
  const float* Wqkv  = (const float*)d_in[1];
  const float* bqkv  = (const float*)d_in[2];
  const float* Wproj = (const float*)d_in[3];
  const float* bproj = (const float*)d_in[4];
  float* out = (float*)d_out;
  unsigned short* ws = (unsigned short*)d_ws;

  unsigned short* xbf    = ws;
  unsigned short* Yw     = xbf;  // alias: x dead after gemm_qkv
  unsigned short* WqkvT  = xbf + 8388608;
  unsigned short* WprojT = WqkvT + 3072 * 1024;
  unsigned short* Qw     = WprojT + 1024 * 1024;
  unsigned short* Kw     = Qw + 8388608;   // [b,h,t,d]
  unsigned short* Vw     = Kw + 8388608;   // (unused -- V written as V^T)
  unsigned short* Vtw    = Vw + 8388608;   // [b,h,d,t], written by gemm_qkv
  (void)Vw;

  prep<<<12288, 256, 0, stream>>>(x, xbf, Wqkv, WqkvT, Wproj, WprojT);
  gemm_qkv<<<dim3(24, 64), 256, 0, stream>>>(xbf, WqkvT, bqkv, Qw, 8192, 3072, 1024);
  attn<<<dim3(16, 64), 256, 0, stream>>>(Qw, Kw, Vtw, Yw);
  gemm_proj<<<dim3(8, 128), 256, 0, stream>>>(Yw, WprojT, bproj, out, 8192, 1024, 1024);
}